// Round 1
// baseline (130.263 us; speedup 1.0000x reference)
//
#include <hip/hip_runtime.h>
#include <math.h>

#define NB   8
#define TD   64
#define TE   1024
#define DDIM 256
#define UDIM 128
#define NSC  16
#define SCHUNK (TE / NSC)   // 64

__device__ __forceinline__ float rcp_fast(float x) {
    return __builtin_amdgcn_rcpf(x);   // v_rcp_f32, ~1 ulp — fine downstream of softmax
}

// ---------------------------------------------------------------------------
// Kernel 1: E = exp(2*(X @ W + b)) for encoder (8192 rows) and decoder (512).
// 16 rows per block, 256 threads. Transposed LDS staging so the per-d read of
// 4 rows is one broadcast ds_read_b128. Thread owns (u-pair, 4 rows) -> 8 FMA
// per d-iter per thread.
// ---------------------------------------------------------------------------
__global__ __launch_bounds__(256) void k_compute_E(
    const float* __restrict__ enc, const float* __restrict__ dec,
    const float* __restrict__ W1, const float* __restrict__ b1,
    const float* __restrict__ W2, const float* __restrict__ b2,
    float* __restrict__ E_enc, float* __restrict__ E_dec)
{
    __shared__ alignas(16) float ldsT[DDIM][20];  // [d][r], r<16, pad->20 (b128-aligned, banks spread)

    const int blk = blockIdx.x;
    const float *W, *bias, *in;
    float *out;
    if (blk < 512) {                    // encoder rows
        in   = enc + (size_t)blk * 16 * DDIM;
        W    = W1;  bias = b1;
        out  = E_enc + (size_t)blk * 16 * UDIM;
    } else {                            // decoder rows
        const int bd = blk - 512;
        in   = dec + (size_t)bd * 16 * DDIM;
        W    = W2;  bias = b2;
        out  = E_dec + (size_t)bd * 16 * UDIM;
    }

    const int tid = threadIdx.x;
    // stage 16x256 input rows transposed (coalesced global read)
    for (int i = tid; i < 16 * DDIM; i += 256) {
        const int r = i >> 8;
        const int d = i & 255;
        ldsT[d][r] = in[i];
    }
    __syncthreads();

    const int u0 = (tid & 63) * 2;      // u-pair
    const int r0 = (tid >> 6) * 4;      // 4 rows per thread, wave-uniform

    float acc[4][2];
    #pragma unroll
    for (int r = 0; r < 4; ++r) { acc[r][0] = 0.f; acc[r][1] = 0.f; }

    #pragma unroll 4
    for (int d = 0; d < DDIM; ++d) {
        const float2 w2 = *(const float2*)(W + d * UDIM + u0);       // coalesced 512B/wave
        const float4 a4 = *(const float4*)(&ldsT[d][r0]);            // wave-uniform broadcast
        acc[0][0] = fmaf(a4.x, w2.x, acc[0][0]); acc[0][1] = fmaf(a4.x, w2.y, acc[0][1]);
        acc[1][0] = fmaf(a4.y, w2.x, acc[1][0]); acc[1][1] = fmaf(a4.y, w2.y, acc[1][1]);
        acc[2][0] = fmaf(a4.z, w2.x, acc[2][0]); acc[2][1] = fmaf(a4.z, w2.y, acc[2][1]);
        acc[3][0] = fmaf(a4.w, w2.x, acc[3][0]); acc[3][1] = fmaf(a4.w, w2.y, acc[3][1]);
    }

    const float k2l2e = 2.0f * 1.4426950408889634f;  // 2*log2(e)
    const float bb0 = bias[u0], bb1 = bias[u0 + 1];
    #pragma unroll
    for (int r = 0; r < 4; ++r) {
        const float e0 = exp2f((acc[r][0] + bb0) * k2l2e);
        const float e1 = exp2f((acc[r][1] + bb1) * k2l2e);
        *(float2*)(out + (size_t)(r0 + r) * UDIM + u0) = make_float2(e0, e1);
    }
}

// ---------------------------------------------------------------------------
// Kernel 2: score + softmax -> attn.
// score'(t,s) = sum_u (-2 V_u) * rcp(1 + E_enc[s,u]*E_dec[t,u])
// (tanh identity; the constant sum(V)+bV shift cancels in softmax).
// Block = (b, t-pair), 1024 threads = one s each. E_dec rows + (-2V) in LDS.
// ---------------------------------------------------------------------------
__global__ __launch_bounds__(1024) void k_score_softmax(
    const float* __restrict__ E_enc, const float* __restrict__ E_dec,
    const float* __restrict__ V, float* __restrict__ attn)
{
    __shared__ alignas(16) float et0[UDIM];
    __shared__ alignas(16) float et1[UDIM];
    __shared__ alignas(16) float mv[UDIM];
    __shared__ float redmax[16][2];
    __shared__ float redsum[16][2];

    const int blk = blockIdx.x;        // 0..255
    const int b   = blk >> 5;
    const int t0  = (blk & 31) * 2;
    const int tid = threadIdx.x;

    if (tid < UDIM)              et0[tid]          = E_dec[(size_t)(b * TD + t0) * UDIM + tid];
    else if (tid < 2 * UDIM)     et1[tid - UDIM]   = E_dec[(size_t)(b * TD + t0 + 1) * UDIM + (tid - UDIM)];
    else if (tid < 3 * UDIM)     mv[tid - 2*UDIM]  = -2.0f * V[tid - 2 * UDIM];
    __syncthreads();

    const int s = tid;
    const float* erow = E_enc + (size_t)(b * TE + s) * UDIM;

    float acc0 = 0.f, acc1 = 0.f;
    #pragma unroll 8
    for (int u = 0; u < UDIM; u += 4) {
        const float4 e  = *(const float4*)(erow + u);
        const float4 a0 = *(const float4*)(&et0[u]);
        const float4 a1 = *(const float4*)(&et1[u]);
        const float4 m  = *(const float4*)(&mv[u]);
        acc0 = fmaf(m.x, rcp_fast(fmaf(e.x, a0.x, 1.f)), acc0);
        acc1 = fmaf(m.x, rcp_fast(fmaf(e.x, a1.x, 1.f)), acc1);
        acc0 = fmaf(m.y, rcp_fast(fmaf(e.y, a0.y, 1.f)), acc0);
        acc1 = fmaf(m.y, rcp_fast(fmaf(e.y, a1.y, 1.f)), acc1);
        acc0 = fmaf(m.z, rcp_fast(fmaf(e.z, a0.z, 1.f)), acc0);
        acc1 = fmaf(m.z, rcp_fast(fmaf(e.z, a1.z, 1.f)), acc1);
        acc0 = fmaf(m.w, rcp_fast(fmaf(e.w, a0.w, 1.f)), acc0);
        acc1 = fmaf(m.w, rcp_fast(fmaf(e.w, a1.w, 1.f)), acc1);
    }

    // ---- block max over 1024 s (two rows at once) ----
    float m0 = acc0, m1 = acc1;
    #pragma unroll
    for (int off = 32; off; off >>= 1) {
        m0 = fmaxf(m0, __shfl_xor(m0, off));
        m1 = fmaxf(m1, __shfl_xor(m1, off));
    }
    const int wv = tid >> 6;
    if ((tid & 63) == 0) { redmax[wv][0] = m0; redmax[wv][1] = m1; }
    __syncthreads();
    float gm0 = -3.4e38f, gm1 = -3.4e38f;
    #pragma unroll
    for (int i = 0; i < 16; ++i) {
        gm0 = fmaxf(gm0, redmax[i][0]);
        gm1 = fmaxf(gm1, redmax[i][1]);
    }

    const float p0 = __expf(acc0 - gm0);
    const float p1 = __expf(acc1 - gm1);

    // ---- block sum ----
    float s0 = p0, s1 = p1;
    #pragma unroll
    for (int off = 32; off; off >>= 1) {
        s0 += __shfl_xor(s0, off);
        s1 += __shfl_xor(s1, off);
    }
    if ((tid & 63) == 0) { redsum[wv][0] = s0; redsum[wv][1] = s1; }
    __syncthreads();
    float gs0 = 0.f, gs1 = 0.f;
    #pragma unroll
    for (int i = 0; i < 16; ++i) { gs0 += redsum[i][0]; gs1 += redsum[i][1]; }

    attn[(size_t)(b * TD + t0)     * TE + s] = p0 * rcp_fast(gs0);
    attn[(size_t)(b * TD + t0 + 1) * TE + s] = p1 * rcp_fast(gs1);
}

// ---------------------------------------------------------------------------
// Kernel 3: context partials over s-chunks.
// Grid = b(8) x tgroup(4 of 16t) x schunk(16 of 64s) = 512 blocks, 256 thr.
// Thread = (d-quad dq, t-quad th). attn tile in LDS; enc read coalesced f4.
// ---------------------------------------------------------------------------
__global__ __launch_bounds__(256) void k_context_part(
    const float* __restrict__ attn, const float* __restrict__ enc,
    float* __restrict__ part)
{
    __shared__ float al[16 * SCHUNK];   // [16 t][64 s] = 4KB

    const int blk = blockIdx.x;
    const int sc  = blk & 15;
    const int tg  = (blk >> 4) & 3;
    const int b   = blk >> 6;
    const int tid = threadIdx.x;
    const int t0  = tg * 16;
    const int s0  = sc * SCHUNK;

    for (int i = tid; i < 16 * SCHUNK; i += 256) {
        const int ti = i >> 6;
        const int si = i & 63;
        al[i] = attn[(size_t)(b * TD + t0 + ti) * TE + s0 + si];
    }
    __syncthreads();

    const int dq = tid & 63;   const int d0 = dq * 4;
    const int th = tid >> 6;   // wave-uniform -> al reads are broadcasts

    float4 acc[4];
    #pragma unroll
    for (int j = 0; j < 4; ++j) acc[j] = make_float4(0.f, 0.f, 0.f, 0.f);

    for (int s = 0; s < SCHUNK; ++s) {
        const float4 e = *(const float4*)(enc + (size_t)(b * TE + s0 + s) * DDIM + d0);
        #pragma unroll
        for (int j = 0; j < 4; ++j) {
            const float a = al[(th * 4 + j) * SCHUNK + s];
            acc[j].x = fmaf(a, e.x, acc[j].x);
            acc[j].y = fmaf(a, e.y, acc[j].y);
            acc[j].z = fmaf(a, e.z, acc[j].z);
            acc[j].w = fmaf(a, e.w, acc[j].w);
        }
    }

    #pragma unroll
    for (int j = 0; j < 4; ++j) {
        const int t = t0 + th * 4 + j;
        *(float4*)(part + ((size_t)(b * TD + t) * NSC + sc) * DDIM + d0) = acc[j];
    }
}

// ---------------------------------------------------------------------------
// Kernel 4: reduce the 16 s-chunk partials -> d_out.
// ---------------------------------------------------------------------------
__global__ __launch_bounds__(256) void k_reduce(
    const float* __restrict__ part, float* __restrict__ out)
{
    const int o  = blockIdx.x * 256 + threadIdx.x;   // 131072 outputs
    const int d  = o & 255;
    const int bt = o >> 8;
    const float* p = part + (size_t)bt * NSC * DDIM + d;
    float s = 0.f;
    #pragma unroll
    for (int i = 0; i < NSC; ++i) s += p[(size_t)i * DDIM];
    out[o] = s;
}

extern "C" void kernel_launch(void* const* d_in, const int* in_sizes, int n_in,
                              void* d_out, int out_size, void* d_ws, size_t ws_size,
                              hipStream_t stream) {
    const float* dec = (const float*)d_in[0];   // [8,64,256]
    const float* enc = (const float*)d_in[1];   // [8,1024,256]
    const float* W1  = (const float*)d_in[2];   // [256,128]
    const float* b1  = (const float*)d_in[3];   // [128]
    const float* W2  = (const float*)d_in[4];   // [256,128]
    const float* b2  = (const float*)d_in[5];   // [128]
    const float* V   = (const float*)d_in[6];   // [128,1]
    // d_in[7] = bV: constant shift, cancels in softmax -> unused.

    float* ws    = (float*)d_ws;
    float* E_enc = ws;                                   // 8*1024*128 = 1048576 f
    float* E_dec = E_enc + (size_t)NB * TE * UDIM;       // 8*64*128   =   65536 f
    float* attn  = E_dec + (size_t)NB * TD * UDIM;       // 8*64*1024  =  524288 f
    float* part  = attn  + (size_t)NB * TD * TE;         // 8*64*16*256= 2097152 f
    // total ws use: ~14.3 MB

    k_compute_E    <<<544, 256,  0, stream>>>(enc, dec, W1, b1, W2, b2, E_enc, E_dec);
    k_score_softmax<<<256, 1024, 0, stream>>>(E_enc, E_dec, V, attn);
    k_context_part <<<512, 256,  0, stream>>>(attn, enc, part);
    k_reduce       <<<512, 256,  0, stream>>>(part, (float*)d_out);
}